// Round 4
// baseline (273.445 us; speedup 1.0000x reference)
//
#include <hip/hip_runtime.h>

// QLIFSpike: x[B,T,C,H,W] f32, mask[B,T,C] i32 -> spikes[B,T,C,H,W] f32
// Sequential over T per (b,c,h,w); parallel over B*C*H*W.
// Constants from reference: TAU=0.5, THRESH=1.0, LB=-3, UB_LEVEL=1, INTERVAL=1.
//
// R4: block == one (b,c) slice (256 threads = 256 float4 = 1024 hw).
//   - mask index is block-uniform -> compiler emits s_load + scalar branch
//     (no per-lane VMEM mask loads, no readfirstlane).
//   - loads plain (x is L3-warm after harness restore; nt would bypass L3),
//     stores nontemporal (pure stream, don't pollute L2).
//   - mask==0 step needs no x: mem stays in {-3..1}; mem*0.5 in [-1.5,0.5]
//     -> spike always 0, clip no-op, just mem=rint(mem*0.5).

#define T_STEPS 10
#define C_CH    128
#define HW_SZ   1024   // 32*32
#define HW4     (HW_SZ / 4)

typedef float vfloat4 __attribute__((ext_vector_type(4)));

__device__ __forceinline__ float qlif_step(float& mem, float xi) {
    mem = mem * 0.5f + xi;                       // leaky integrate (×0.5 exact)
    float spike = (mem > 1.0f) ? 1.0f : 0.0f;    // threshold fire
    float m = (spike > 0.0f) ? 0.0f : mem;       // hard reset
    // qmem: clip(round(m), -3, 1); rintf == round-half-to-even == np.round
    mem = fminf(fmaxf(rintf(m), -3.0f), 1.0f);
    return spike;
}

__global__ __launch_bounds__(HW4) void qlif_kernel(
        const float* __restrict__ x,
        const int*   __restrict__ mask,
        float*       __restrict__ out)
{
    // one block per (b,c): blockIdx.x = b*C + c
    const int bc  = blockIdx.x;
    const int c   = bc & (C_CH - 1);
    const int b   = bc >> 7;                     // bc / C_CH

    // element offset of (b, t=0, c, hw4*4)
    const long base  = ((long)b * T_STEPS * C_CH + c) * HW_SZ + (long)threadIdx.x * 4;
    const int  mbase = b * T_STEPS * C_CH + c;   // block-uniform -> SGPR
    const long tstride = (long)C_CH * HW_SZ;     // 131072 elements per t

    // Block-uniform mask preload: compiler emits s_load_dword (scalar path).
    int mval[T_STEPS];
    #pragma unroll
    for (int t = 0; t < T_STEPS; ++t)
        mval[t] = mask[mbase + t * C_CH];

    float4 mem = make_float4(0.f, 0.f, 0.f, 0.f);

    #pragma unroll
    for (int t = 0; t < T_STEPS; ++t) {
        vfloat4 s;
        if (mval[t] != 0) {                      // scalar branch (uniform)
            const vfloat4 xi = *reinterpret_cast<const vfloat4*>(x + base + t * tstride);
            s.x = qlif_step(mem.x, xi.x);
            s.y = qlif_step(mem.y, xi.y);
            s.z = qlif_step(mem.z, xi.z);
            s.w = qlif_step(mem.w, xi.w);
        } else {
            // masked step: no spike, no reset, clip no-op
            mem.x = rintf(mem.x * 0.5f);
            mem.y = rintf(mem.y * 0.5f);
            mem.z = rintf(mem.z * 0.5f);
            mem.w = rintf(mem.w * 0.5f);
            s.x = 0.f; s.y = 0.f; s.z = 0.f; s.w = 0.f;
        }
        vfloat4* op = reinterpret_cast<vfloat4*>(out + base + t * tstride);
        __builtin_nontemporal_store(s, op);
    }
}

extern "C" void kernel_launch(void* const* d_in, const int* in_sizes, int n_in,
                              void* d_out, int out_size, void* d_ws, size_t ws_size,
                              hipStream_t stream) {
    const float* x    = (const float*)d_in[0];
    const int*   mask = (const int*)d_in[1];
    // d_in[2] (conv_input) is unused by the reference computation.
    float* out = (float*)d_out;

    long total = (long)in_sizes[0];                       // B*T*C*HW
    int  B     = (int)(total / ((long)T_STEPS * C_CH * HW_SZ));
    int  grid  = B * C_CH;                                // one block per (b,c)

    qlif_kernel<<<grid, HW4, 0, stream>>>(x, mask, out);
}

// Round 5
// 264.578 us; speedup vs baseline: 1.0335x; 1.0335x over previous
//
#include <hip/hip_runtime.h>

// QLIFSpike: x[B,T,C,H,W] f32, mask[B,T,C] i32 -> spikes[B,T,C,H,W] f32
// Sequential over T per (b,c,h,w); parallel over B*C*H*W.
// Constants from reference: TAU=0.5, THRESH=1.0, LB=-3, UB_LEVEL=1, INTERVAL=1.
//
// R5 = best-of-both:
//   - block == one (b,c) slice (256 threads × float4 = 1024 hw): mask index
//     is block-uniform -> s_load + scalar branch, no per-lane mask VMEM.
//   - nontemporal loads AND stores (R2-measured win): the harness's 671 MB
//     poison fill evicts L3 every replay, so x is HBM-cold; nt avoids
//     useless cache allocation on a touch-once stream. (R4 removed nt on
//     loads -> +8.6 us, confirming the hint's value.)
//   - mask==0 step skips the x load entirely: post-qmem mem ∈ {-3..1},
//     mem*0.5 ∈ [-1.5,0.5] -> spike always 0, reset/clip no-ops,
//     update is just mem = rint(mem*0.5). Halves expected read traffic.

#define T_STEPS 10
#define C_CH    128
#define HW_SZ   1024   // 32*32
#define HW4     (HW_SZ / 4)

typedef float vfloat4 __attribute__((ext_vector_type(4)));

__device__ __forceinline__ float qlif_step(float& mem, float xi) {
    mem = mem * 0.5f + xi;                       // leaky integrate (×0.5 exact)
    float spike = (mem > 1.0f) ? 1.0f : 0.0f;    // threshold fire
    float m = (spike > 0.0f) ? 0.0f : mem;       // hard reset
    // qmem: clip(round(m), -3, 1); rintf == round-half-to-even == np.round
    mem = fminf(fmaxf(rintf(m), -3.0f), 1.0f);
    return spike;
}

__global__ __launch_bounds__(HW4) void qlif_kernel(
        const float* __restrict__ x,
        const int*   __restrict__ mask,
        float*       __restrict__ out)
{
    // one block per (b,c): blockIdx.x = b*C + c
    const int bc = blockIdx.x;
    const int c  = bc & (C_CH - 1);
    const int b  = bc >> 7;                      // bc / C_CH

    // element offset of (b, t=0, c, hw4*4)
    const long base  = ((long)b * T_STEPS * C_CH + c) * HW_SZ + (long)threadIdx.x * 4;
    const int  mbase = b * T_STEPS * C_CH + c;   // block-uniform -> SGPR
    const long tstride = (long)C_CH * HW_SZ;     // 131072 elements per t

    // Block-uniform mask preload: scalar loads, issued before the recurrence.
    int mval[T_STEPS];
    #pragma unroll
    for (int t = 0; t < T_STEPS; ++t)
        mval[t] = mask[mbase + t * C_CH];

    float4 mem = make_float4(0.f, 0.f, 0.f, 0.f);

    #pragma unroll
    for (int t = 0; t < T_STEPS; ++t) {
        vfloat4 s;
        if (mval[t] != 0) {                      // scalar (uniform) branch
            const vfloat4* xp = reinterpret_cast<const vfloat4*>(x + base + t * tstride);
            vfloat4 xi = __builtin_nontemporal_load(xp);
            s.x = qlif_step(mem.x, xi.x);
            s.y = qlif_step(mem.y, xi.y);
            s.z = qlif_step(mem.z, xi.z);
            s.w = qlif_step(mem.w, xi.w);
        } else {
            // masked step: no spike, no reset, clip no-op
            mem.x = rintf(mem.x * 0.5f);
            mem.y = rintf(mem.y * 0.5f);
            mem.z = rintf(mem.z * 0.5f);
            mem.w = rintf(mem.w * 0.5f);
            s.x = 0.f; s.y = 0.f; s.z = 0.f; s.w = 0.f;
        }
        vfloat4* op = reinterpret_cast<vfloat4*>(out + base + t * tstride);
        __builtin_nontemporal_store(s, op);
    }
}

extern "C" void kernel_launch(void* const* d_in, const int* in_sizes, int n_in,
                              void* d_out, int out_size, void* d_ws, size_t ws_size,
                              hipStream_t stream) {
    const float* x    = (const float*)d_in[0];
    const int*   mask = (const int*)d_in[1];
    // d_in[2] (conv_input) is unused by the reference computation.
    float* out = (float*)d_out;

    long total = (long)in_sizes[0];                       // B*T*C*HW
    int  B     = (int)(total / ((long)T_STEPS * C_CH * HW_SZ));
    int  grid  = B * C_CH;                                // one block per (b,c)

    qlif_kernel<<<grid, HW4, 0, stream>>>(x, mask, out);
}